// Round 21
// baseline (71.660 us; speedup 1.0000x reference)
//
#include <hip/hip_runtime.h>
#include <hip/hip_bf16.h>
#include <stdint.h>

constexpr int kB = 8, kH = 8, kS = 1024, kD = 512, kDH = 64;
constexpr float kNeg = -1e9f;
constexpr float kScaleLog2e = 0.125f * 1.4426950408889634f;

typedef __attribute__((ext_vector_type(8))) short bf16x8;
typedef __attribute__((ext_vector_type(8))) unsigned short u16x8;
typedef __attribute__((ext_vector_type(4))) float f32x4;
typedef __attribute__((ext_vector_type(4))) unsigned short u16x4;

__device__ __forceinline__ unsigned short f2bf(float f) {
  union { float f; unsigned int u; } a; a.f = f;
  return (unsigned short)((a.u + 0x7FFFu + ((a.u >> 16) & 1u)) >> 16);
}
__device__ __forceinline__ float bf2f(unsigned short u) {
  union { unsigned int u; float f; } a; a.u = ((unsigned int)u) << 16;
  return a.f;
}
__device__ __forceinline__ unsigned int pk2bf(float lo, float hi) {
  union { __hip_bfloat162 h; unsigned int u; } cv;
  cv.h = __float22bfloat162_rn(make_float2(lo, hi));
  return cv.u;
}
// Pinned global loads (inline asm: cannot be sunk/CSE'd/re-materialized).
__device__ __forceinline__ uint4 gload16(const void* p) {
  uint4 r;
  asm volatile("global_load_dwordx4 %0, %1, off" : "=v"(r) : "v"(p));
  return r;
}
__device__ __forceinline__ int gload4(const void* p) {
  int r;
  asm volatile("global_load_dword %0, %1, off" : "=v"(r) : "v"(p));
  return r;
}
#define WAIT_VMCNT(N) do { \
  asm volatile("s_waitcnt vmcnt(" #N ")" ::: "memory"); \
  __builtin_amdgcn_sched_barrier(0); } while (0)

__device__ __forceinline__ uint4 cvt4(uint4 a, uint4 b) {
  uint4 r;
  r.x = pk2bf(__uint_as_float(a.x), __uint_as_float(a.y));
  r.y = pk2bf(__uint_as_float(a.z), __uint_as_float(a.w));
  r.z = pk2bf(__uint_as_float(b.x), __uint_as_float(b.y));
  r.w = pk2bf(__uint_as_float(b.z), __uint_as_float(b.w));
  return r;
}

#if __has_builtin(__builtin_amdgcn_exp2f)
#define EXP2F(x) __builtin_amdgcn_exp2f(x)
#else
#define EXP2F(x) exp2f(x)
#endif

// ---------------------------------------------------------------------------
// Kernel 0: W (3x512x512 f32) -> bf16 into ws+32MB.
// ---------------------------------------------------------------------------
__global__ __launch_bounds__(256)
void wcvt_kernel(const float* __restrict__ wq, const float* __restrict__ wk,
                 const float* __restrict__ wv, unsigned short* __restrict__ wout)
{
  const int tid = blockIdx.x * 256 + threadIdx.x;   // 0..196607
  const int z = tid >> 16;
  const int i = (tid & 65535) * 4;
  const float* W = (z == 0) ? wq : (z == 1) ? wk : wv;
  float4 v4 = *(const float4*)(W + i);
  u16x4 pk;
  pk[0] = f2bf(v4.x); pk[1] = f2bf(v4.y); pk[2] = f2bf(v4.z); pk[3] = f2bf(v4.w);
  *(u16x4*)(wout + (size_t)z * 262144 + i) = pk;
}

// ---------------------------------------------------------------------------
// Kernel 1: C = relu(X @ W^T + bias). SINGLE-BUFFER + phase-split: 36.9 KB
// LDS => 4 blocks/CU (16 waves/CU, 2x R17's TLP) while keeping the 4-phase
// compute with setprio and quarter-issue interleave. 1-deep pinned prefetch:
// tile i+1's 12 loads issue inside tile i's compute phases and land across
// the end barrier; vmcnt(0) drains at the write (single set in flight).
// GEMM was latency-bound (all pipes <17%): occupancy is the orthogonal lever
// never combined with this schedule (R8: 4 blk/CU coarse = 40.7us; R17:
// 2 blk/CU phased = 37us).
//   Q,K: [b*H+h][s][64]; V: [b*H+h][d][s] with s k-permuted per 64-block.
// ---------------------------------------------------------------------------
__global__ __launch_bounds__(256)
void qkv_gemm_kernel(const float* __restrict__ xq, const float* __restrict__ xk,
                     const float* __restrict__ xv,
                     const unsigned short* __restrict__ wbf,
                     const float* __restrict__ bq, const float* __restrict__ bk,
                     const float* __restrict__ bv,
                     unsigned short* __restrict__ wsout)
{
  __shared__ __align__(16) unsigned short As[128][72];
  __shared__ __align__(16) unsigned short Bs[128][72];

  const int bid = blockIdx.x;
  const int xcd = bid & 7;
  const int j = bid >> 3;
  const int x = j & 3;
  const int g = (j >> 2) * 8 + xcd;        // 0..191
  const int z = g >> 6;                    // 0..2
  const int y = g & 63;                    // 0..63

  const float* X    = (z == 0) ? xq : (z == 1) ? xk : xv;
  const unsigned short* Wb = wbf + (size_t)z * 262144;
  const float* bias = (z == 0) ? bq : (z == 1) ? bk : bv;
  unsigned short* out = wsout + (size_t)z * (kB * kS * kD);

  const int m0 = y * 128;
  const int n0 = x * 128;
  const int t = threadIdx.x;
  const int lane = t & 63;
  const int w = t >> 6;
  const int wr = w >> 1, wc = w & 1;
  const int l16 = lane & 15, lg = lane >> 4;

  const int row = t >> 3, c8 = (t & 7) * 8;
  const float* Xr = X + (size_t)(m0 + row) * kD + c8;
  const unsigned short* Wr = Wb + (size_t)(n0 + row) * kD + c8;

  f32x4 acc[4][4] = {};
  uint4 pa0, pa1, pa2, pa3, pa4, pa5, pa6, pa7, pb0, pb1, pb2, pb3;

  auto issueAll = [&](int kt) {
    pa0 = gload16(Xr + kt);            pa1 = gload16(Xr + kt + 4);
    pa2 = gload16(Xr + 32 * kD + kt);  pa3 = gload16(Xr + 32 * kD + kt + 4);
    pa4 = gload16(Xr + 64 * kD + kt);  pa5 = gload16(Xr + 64 * kD + kt + 4);
    pa6 = gload16(Xr + 96 * kD + kt);  pa7 = gload16(Xr + 96 * kD + kt + 4);
    pb0 = gload16(Wr + kt);            pb1 = gload16(Wr + 32 * kD + kt);
    pb2 = gload16(Wr + 64 * kD + kt);  pb3 = gload16(Wr + 96 * kD + kt);
  };
  auto issue1 = [&](int kt) {
    pa0 = gload16(Xr + kt);            pa1 = gload16(Xr + kt + 4);
    pa2 = gload16(Xr + 32 * kD + kt);
  };
  auto issue2 = [&](int kt) {
    pa3 = gload16(Xr + 32 * kD + kt + 4);
    pa4 = gload16(Xr + 64 * kD + kt);  pa5 = gload16(Xr + 64 * kD + kt + 4);
  };
  auto issue3 = [&](int kt) {
    pa6 = gload16(Xr + 96 * kD + kt);  pa7 = gload16(Xr + 96 * kD + kt + 4);
    pb0 = gload16(Wr + kt);
  };
  auto issue4 = [&](int kt) {
    pb1 = gload16(Wr + 32 * kD + kt);
    pb2 = gload16(Wr + 64 * kD + kt);  pb3 = gload16(Wr + 96 * kD + kt);
  };
  auto lds_write = [&]() {
    *(uint4*)&As[row][c8]      = cvt4(pa0, pa1);
    *(uint4*)&As[row + 32][c8] = cvt4(pa2, pa3);
    *(uint4*)&As[row + 64][c8] = cvt4(pa4, pa5);
    *(uint4*)&As[row + 96][c8] = cvt4(pa6, pa7);
    *(uint4*)&Bs[row][c8]      = pb0;
    *(uint4*)&Bs[row + 32][c8] = pb1;
    *(uint4*)&Bs[row + 64][c8] = pb2;
    *(uint4*)&Bs[row + 96][c8] = pb3;
  };

  // 4-phase compute; interleaves quarter issues of the NEXT tile (KT>=0).
  auto compute_phased = [&](int KT) {
    bf16x8 av0, av1, av2, av3, bv0, bv1;
    // phase 1: kk=0, nf=0,1
    av0 = *(const bf16x8*)&As[wr * 64 +  0 + l16][lg * 8];
    av1 = *(const bf16x8*)&As[wr * 64 + 16 + l16][lg * 8];
    av2 = *(const bf16x8*)&As[wr * 64 + 32 + l16][lg * 8];
    av3 = *(const bf16x8*)&As[wr * 64 + 48 + l16][lg * 8];
    bv0 = *(const bf16x8*)&Bs[wc * 64 +  0 + l16][lg * 8];
    bv1 = *(const bf16x8*)&Bs[wc * 64 + 16 + l16][lg * 8];
    if (KT >= 0) issue1(KT);
    __builtin_amdgcn_s_setprio(1);
    acc[0][0] = __builtin_amdgcn_mfma_f32_16x16x32_bf16(bv0, av0, acc[0][0], 0, 0, 0);
    acc[1][0] = __builtin_amdgcn_mfma_f32_16x16x32_bf16(bv0, av1, acc[1][0], 0, 0, 0);
    acc[2][0] = __builtin_amdgcn_mfma_f32_16x16x32_bf16(bv0, av2, acc[2][0], 0, 0, 0);
    acc[3][0] = __builtin_amdgcn_mfma_f32_16x16x32_bf16(bv0, av3, acc[3][0], 0, 0, 0);
    acc[0][1] = __builtin_amdgcn_mfma_f32_16x16x32_bf16(bv1, av0, acc[0][1], 0, 0, 0);
    acc[1][1] = __builtin_amdgcn_mfma_f32_16x16x32_bf16(bv1, av1, acc[1][1], 0, 0, 0);
    acc[2][1] = __builtin_amdgcn_mfma_f32_16x16x32_bf16(bv1, av2, acc[2][1], 0, 0, 0);
    acc[3][1] = __builtin_amdgcn_mfma_f32_16x16x32_bf16(bv1, av3, acc[3][1], 0, 0, 0);
    __builtin_amdgcn_s_setprio(0);
    __syncthreads();
    // phase 2: kk=0, nf=2,3
    bv0 = *(const bf16x8*)&Bs[wc * 64 + 32 + l16][lg * 8];
    bv1 = *(const bf16x8*)&Bs[wc * 64 + 48 + l16][lg * 8];
    if (KT >= 0) issue2(KT);
    __builtin_amdgcn_s_setprio(1);
    acc[0][2] = __builtin_amdgcn_mfma_f32_16x16x32_bf16(bv0, av0, acc[0][2], 0, 0, 0);
    acc[1][2] = __builtin_amdgcn_mfma_f32_16x16x32_bf16(bv0, av1, acc[1][2], 0, 0, 0);
    acc[2][2] = __builtin_amdgcn_mfma_f32_16x16x32_bf16(bv0, av2, acc[2][2], 0, 0, 0);
    acc[3][2] = __builtin_amdgcn_mfma_f32_16x16x32_bf16(bv0, av3, acc[3][2], 0, 0, 0);
    acc[0][3] = __builtin_amdgcn_mfma_f32_16x16x32_bf16(bv1, av0, acc[0][3], 0, 0, 0);
    acc[1][3] = __builtin_amdgcn_mfma_f32_16x16x32_bf16(bv1, av1, acc[1][3], 0, 0, 0);
    acc[2][3] = __builtin_amdgcn_mfma_f32_16x16x32_bf16(bv1, av2, acc[2][3], 0, 0, 0);
    acc[3][3] = __builtin_amdgcn_mfma_f32_16x16x32_bf16(bv1, av3, acc[3][3], 0, 0, 0);
    __builtin_amdgcn_s_setprio(0);
    __syncthreads();
    // phase 3: kk=1, nf=0,1
    av0 = *(const bf16x8*)&As[wr * 64 +  0 + l16][32 + lg * 8];
    av1 = *(const bf16x8*)&As[wr * 64 + 16 + l16][32 + lg * 8];
    av2 = *(const bf16x8*)&As[wr * 64 + 32 + l16][32 + lg * 8];
    av3 = *(const bf16x8*)&As[wr * 64 + 48 + l16][32 + lg * 8];
    bv0 = *(const bf16x8*)&Bs[wc * 64 +  0 + l16][32 + lg * 8];
    bv1 = *(const bf16x8*)&Bs[wc * 64 + 16 + l16][32 + lg * 8];
    if (KT >= 0) issue3(KT);
    __builtin_amdgcn_s_setprio(1);
    acc[0][0] = __builtin_amdgcn_mfma_f32_16x16x32_bf16(bv0, av0, acc[0][0], 0, 0, 0);
    acc[1][0] = __builtin_amdgcn_mfma_f32_16x16x32_bf16(bv0, av1, acc[1][0], 0, 0, 0);
    acc[2][0] = __builtin_amdgcn_mfma_f32_16x16x32_bf16(bv0, av2, acc[2][0], 0, 0, 0);
    acc[3][0] = __builtin_amdgcn_mfma_f32_16x16x32_bf16(bv0, av3, acc[3][0], 0, 0, 0);
    acc[0][1] = __builtin_amdgcn_mfma_f32_16x16x32_bf16(bv1, av0, acc[0][1], 0, 0, 0);
    acc[1][1] = __builtin_amdgcn_mfma_f32_16x16x32_bf16(bv1, av1, acc[1][1], 0, 0, 0);
    acc[2][1] = __builtin_amdgcn_mfma_f32_16x16x32_bf16(bv1, av2, acc[2][1], 0, 0, 0);
    acc[3][1] = __builtin_amdgcn_mfma_f32_16x16x32_bf16(bv1, av3, acc[3][1], 0, 0, 0);
    __builtin_amdgcn_s_setprio(0);
    __syncthreads();
    // phase 4: kk=1, nf=2,3
    bv0 = *(const bf16x8*)&Bs[wc * 64 + 32 + l16][32 + lg * 8];
    bv1 = *(const bf16x8*)&Bs[wc * 64 + 48 + l16][32 + lg * 8];
    if (KT >= 0) issue4(KT);
    __builtin_amdgcn_s_setprio(1);
    acc[0][2] = __builtin_amdgcn_mfma_f32_16x16x32_bf16(bv0, av0, acc[0][2], 0, 0, 0);
    acc[1][2] = __builtin_amdgcn_mfma_f32_16x16x32_bf16(bv0, av1, acc[1][2], 0, 0, 0);
    acc[2][2] = __builtin_amdgcn_mfma_f32_16x16x32_bf16(bv0, av2, acc[2][2], 0, 0, 0);
    acc[3][2] = __builtin_amdgcn_mfma_f32_16x16x32_bf16(bv0, av3, acc[3][2], 0, 0, 0);
    acc[0][3] = __builtin_amdgcn_mfma_f32_16x16x32_bf16(bv1, av0, acc[0][3], 0, 0, 0);
    acc[1][3] = __builtin_amdgcn_mfma_f32_16x16x32_bf16(bv1, av1, acc[1][3], 0, 0, 0);
    acc[2][3] = __builtin_amdgcn_mfma_f32_16x16x32_bf16(bv1, av2, acc[2][3], 0, 0, 0);
    acc[3][3] = __builtin_amdgcn_mfma_f32_16x16x32_bf16(bv1, av3, acc[3][3], 0, 0, 0);
    __builtin_amdgcn_s_setprio(0);
  };

  issueAll(0);
#pragma unroll
  for (int i = 0; i < 8; ++i) {
    WAIT_VMCNT(0);               // tile i's 12 loads landed (single set)
    lds_write();
    __syncthreads();             // writes visible to all waves
    compute_phased(i < 7 ? (i + 1) * 64 : -1);
    __syncthreads();             // reads done before next overwrite
  }

  if (z == 2) {
    const int mmbase = m0 + wr * 64;
    const int b_ = mmbase >> 10, sbase = mmbase & 1023;
#pragma unroll
    for (int nf = 0; nf < 4; ++nf) {
#pragma unroll
      for (int r = 0; r < 4; ++r) {
        const int n = n0 + wc * 64 + nf * 16 + lg * 4 + r;
        const float bval = bias[n];
        const int h = n >> 6, dd = n & 63;
        u16x4 pk;
#pragma unroll
        for (int mf = 0; mf < 4; ++mf) {
          float vv = acc[mf][nf][r] + bval;
          vv = vv > 0.f ? vv : 0.f;
          pk[mf] = f2bf(vv);
        }
        *(u16x4*)&out[((size_t)((b_ * kH + h) * kDH + dd)) * kS + sbase + l16 * 4] = pk;
      }
    }
  } else {
#pragma unroll
    for (int mf = 0; mf < 4; ++mf) {
      const int mm = m0 + wr * 64 + mf * 16 + l16;
      const int b_ = mm >> 10, s = mm & 1023;
#pragma unroll
      for (int nf = 0; nf < 4; ++nf) {
        const int nbase = n0 + wc * 64 + nf * 16 + lg * 4;
        const int h = nbase >> 6, dd = nbase & 63;
        u16x4 pk;
#pragma unroll
        for (int r = 0; r < 4; ++r) {
          float vv = acc[mf][nf][r] + bias[nbase + r];
          vv = vv > 0.f ? vv : 0.f;
          pk[r] = f2bf(vv);
        }
        *(u16x4*)&out[((size_t)(b_ * kH + h) * kS + s) * kDH + dd] = pk;
      }
    }
  }
}

// ---------------------------------------------------------------------------
// Kernel 2: flash attention (R19 verbatim: pad-68 LDS = 51.5KB = 3 blk/CU,
// T5 setprio, bf16 y). 512 blocks (bh x 8 q-tiles of 128 rows), 4 waves x
// 32 q-rows; 2-deep pinned prefetch, counted vmcnt(5); LDS dbuf.
// ---------------------------------------------------------------------------
__global__ __launch_bounds__(256)
void attn_kernel(const unsigned short* __restrict__ ws,
                 const int* __restrict__ key_mask,
                 unsigned short* __restrict__ ybf)
{
  __shared__ __align__(16) unsigned short Ks[2][64][68];
  __shared__ __align__(16) unsigned short Vts[2][64][68];
  __shared__ __align__(16) unsigned short Ps[4][32][68];
  __shared__ float kmadd[2][64];

  const unsigned short* Qw = ws;
  const unsigned short* Kw = ws + (size_t)1 * kB * kS * kD;
  const unsigned short* Vw = ws + (size_t)2 * kB * kS * kD;

  const int bid = blockIdx.x;
  const int xcd = bid & 7;
  const int j = bid >> 3;
  const int qx = j & 7;
  const int bh = (j >> 3) * 8 + xcd;

  const int q0 = qx * 128;
  const int t = threadIdx.x;
  const int w = t >> 6, lane = t & 63;
  const int l16 = lane & 15, lg = lane >> 4;
  const int b_ = bh / kH, h = bh % kH;

  const unsigned short* Qb = Qw + ((size_t)bh * kS + q0) * kDH;
  const unsigned short* Kb = Kw + (size_t)bh * kS * kDH;
  const unsigned short* Vb = Vw + (size_t)bh * kDH * kS;
  const int* km = key_mask + (bh % kB) * kS;

  const int srow = t >> 3, sc8 = (t & 7) * 8;
  const unsigned short* KbR0 = Kb + (size_t)srow * kDH + sc8;
  const unsigned short* KbR1 = Kb + (size_t)(srow + 32) * kDH + sc8;
  const unsigned short* VbR0 = Vb + (size_t)srow * kS + sc8;
  const unsigned short* VbR1 = Vb + (size_t)(srow + 32) * kS + sc8;

  bf16x8 aq[2][2];
#pragma unroll
  for (int u = 0; u < 2; ++u)
#pragma unroll
    for (int kk = 0; kk < 2; ++kk)
      aq[u][kk] = *(const bf16x8*)(Qb + (size_t)(w * 32 + u * 16 + l16) * kDH + kk * 32 + lg * 8);

  bf16x8 vone;
#pragma unroll
  for (int jj = 0; jj < 8; ++jj) vone[jj] = (short)0x3F80;

  f32x4 o[2][4] = {};
  f32x4 lacc[2] = {};

  uint4 ka0, ka1, va0, va1; int kma;
  uint4 kb0, kb1, vb0, vb1; int kmb;

  auto issueA = [&](int kv0) {
    ka0 = gload16(KbR0 + (size_t)kv0 * kDH);
    ka1 = gload16(KbR1 + (size_t)kv0 * kDH);
    va0 = gload16(VbR0 + kv0);
    va1 = gload16(VbR1 + kv0);
    kma = gload4(km + kv0 + (t & 63));
  };
  auto issueB = [&](int kv0) {
    kb0 = gload16(KbR0 + (size_t)kv0 * kDH);
    kb1 = gload16(KbR1 + (size_t)kv0 * kDH);
    vb0 = gload16(VbR0 + kv0);
    vb1 = gload16(VbR1 + kv0);
    kmb = gload4(km + kv0 + (t & 63));
  };
  auto writeA = [&]() {
    *(uint4*)&Ks[0][srow][sc8]       = ka0;
    *(uint4*)&Ks[0][srow + 32][sc8]  = ka1;
    *(uint4*)&Vts[0][srow][sc8]      = va0;
    *(uint4*)&Vts[0][srow + 32][sc8] = va1;
    if (t < 64) kmadd[0][t] = kma ? 0.f : kNeg;
  };
  auto writeB = [&]() {
    *(uint4*)&Ks[1][srow][sc8]       = kb0;
    *(uint4*)&Ks[1][srow + 32][sc8]  = kb1;
    *(uint4*)&Vts[1][srow][sc8]      = vb0;
    *(uint4*)&Vts[1][srow + 32][sc8] = vb1;
    if (t < 64) kmadd[1][t] = kmb ? 0.f : kNeg;
  };
  auto compute = [&](int buf) {
    f32x4 sc[2][4] = {};
    __builtin_amdgcn_s_setprio(1);
#pragma unroll
    for (int kk = 0; kk < 2; ++kk) {
#pragma unroll
      for (int nf = 0; nf < 4; ++nf) {
        bf16x8 bfr = *(const bf16x8*)&Ks[buf][nf * 16 + l16][kk * 32 + lg * 8];
#pragma unroll
        for (int u = 0; u < 2; ++u)
          sc[u][nf] = __builtin_amdgcn_mfma_f32_16x16x32_bf16(aq[u][kk], bfr, sc[u][nf], 0, 0, 0);
      }
    }
    __builtin_amdgcn_s_setprio(0);
    float madd[4];
#pragma unroll
    for (int nf = 0; nf < 4; ++nf) madd[nf] = kmadd[buf][nf * 16 + l16];
#pragma unroll
    for (int u = 0; u < 2; ++u) {
#pragma unroll
      for (int r = 0; r < 4; ++r) {
        const float p0 = EXP2F(fmaf(sc[u][0][r], kScaleLog2e, madd[0]));
        const float p1 = EXP2F(fmaf(sc[u][1][r], kScaleLog2e, madd[1]));
        const float p2 = EXP2F(fmaf(sc[u][2][r], kScaleLog2e, madd[2]));
        const float p3 = EXP2F(fmaf(sc[u][3][r], kScaleLog2e, madd[3]));
        const int prow = u * 16 + lg * 4 + r;
        uint2 pw;
        pw.x = __builtin_amdgcn_perm(__float_as_uint(p1), __float_as_uint(p0), 0x07060302u);
        pw.y = __builtin_amdgcn_perm(__float_as_uint(p3), __float_as_uint(p2), 0x07060302u);
        *(uint2*)&Ps[w][prow][l16 * 4] = pw;
      }
    }
    __builtin_amdgcn_s_setprio(1);
#pragma unroll
    for (int kk = 0; kk < 2; ++kk) {
      bf16x8 a0 = *(const bf16x8*)&Ps[w][l16][kk * 32 + lg * 8];
      bf16x8 a1 = *(const bf16x8*)&Ps[w][16 + l16][kk * 32 + lg * 8];
#pragma unroll
      for (int nd = 0; nd < 4; ++nd) {
        bf16x8 bfr = *(const bf16x8*)&Vts[buf][nd * 16 + l16][kk * 32 + lg * 8];
        o[0][nd] = __builtin_amdgcn_mfma_f32_16x16x32_bf16(a0, bfr, o[0][nd], 0, 0, 0);
        o[1][nd] = __builtin_amdgcn_mfma_f32_16x16x32_bf16(a1, bfr, o[1][nd], 0, 0, 0);
      }
      lacc[0] = __builtin_amdgcn_mfma_f32_16x16x32_bf16(a0, vone, lacc[0], 0, 0, 0);
      lacc[1] = __builtin_amdgcn_mfma_f32_16x16x32_bf16(a1, vone, lacc[1], 0, 0, 0);
    }
    __builtin_amdgcn_s_setprio(0);
  };

  issueA(0);
  issueB(64);
  for (int i = 0; i < 14; i += 2) {
    WAIT_VMCNT(5);
    writeA();
    issueA((i + 2) * 64);
    __syncthreads();
    compute(0);
    WAIT_VMCNT(5);
    writeB();
    issueB((i + 3) * 64);
    __syncthreads();
    compute(1);
  }
  WAIT_VMCNT(5);
  writeA();
  __syncthreads();
  compute(0);
  WAIT_VMCNT(0);
  writeB();
  __syncthreads();
  compute(1);

#pragma unroll
  for (int u = 0; u < 2; ++u) {
    float rinv[4];
#pragma unroll
    for (int r = 0; r < 4; ++r) rinv[r] = 1.f / lacc[u][r];
#pragma unroll
    for (int nd = 0; nd < 4; ++nd) {
#pragma unroll
      for (int r = 0; r < 4; ++r) {
        const int srowq = q0 + w * 32 + u * 16 + lg * 4 + r;
        ybf[((size_t)b_ * kS + srowq) * kD + h * kDH + nd * 16 + l16] =
            f2bf(o[u][nd][r] * rinv[r]);
      }
    }
  }
}

// ---------------------------------------------------------------------------
// Kernel 3: out = LN(qmask*y + q) * gamma + beta. y read as bf16 from ws.
// ---------------------------------------------------------------------------
__global__ __launch_bounds__(256)
void ln_kernel(const unsigned short* __restrict__ ybf, const float* __restrict__ q,
               const int* __restrict__ qmask,
               const float* __restrict__ gamma, const float* __restrict__ beta,
               float* __restrict__ out)
{
  const int w = threadIdx.x >> 6, lane = threadIdx.x & 63;
  const int row = blockIdx.x * 4 + w;            // 0..8191
  const int b_ = row >> 10, s = row & 1023;
  const int d0 = lane * 8;
  const int h = d0 >> 6;

  const unsigned short* yp = ybf + (size_t)row * kD + d0;
  const float* qp = q + (size_t)row * kD + d0;
  const int qm = qmask[((b_ * kH + h) % kB) * kS + s];

  u16x8 yv = *(const u16x8*)yp;
  float4 q0 = *(const float4*)qp, q1 = *(const float4*)(qp + 4);
  float vals[8];
#pragma unroll
  for (int jj = 0; jj < 8; ++jj) vals[jj] = bf2f(yv[jj]);
  float qs[8]   = { q0.x, q0.y, q0.z, q0.w, q1.x, q1.y, q1.z, q1.w };

  float sum = 0.f, ss = 0.f;
#pragma unroll
  for (int jj = 0; jj < 8; ++jj) {
    const float val = (qm ? vals[jj] : 0.f) + qs[jj];
    vals[jj] = val; sum += val; ss += val * val;
  }
#pragma unroll
  for (int off = 1; off < 64; off <<= 1) {
    sum += __shfl_xor(sum, off);
    ss  += __shfl_xor(ss, off);
  }
  const float mu = sum * (1.f / kD);
  const float var = ss * (1.f / kD) - mu * mu;
  const float rstd = rsqrtf(var + 1e-6f);

  float4 g0 = *(const float4*)(gamma + d0), g1 = *(const float4*)(gamma + d0 + 4);
  float4 be0 = *(const float4*)(beta + d0), be1 = *(const float4*)(beta + d0 + 4);
  float gs[8] = { g0.x, g0.y, g0.z, g0.w, g1.x, g1.y, g1.z, g1.w };
  float bs[8] = { be0.x, be0.y, be0.z, be0.w, be1.x, be1.y, be1.z, be1.w };

  float4 o0, o1;
  o0.x = gs[0] * (vals[0] - mu) * rstd + bs[0];
  o0.y = gs[1] * (vals[1] - mu) * rstd + bs[1];
  o0.z = gs[2] * (vals[2] - mu) * rstd + bs[2];
  o0.w = gs[3] * (vals[3] - mu) * rstd + bs[3];
  o1.x = gs[4] * (vals[4] - mu) * rstd + bs[4];
  o1.y = gs[5] * (vals[5] - mu) * rstd + bs[5];
  o1.z = gs[6] * (vals[6] - mu) * rstd + bs[6];
  o1.w = gs[7] * (vals[7] - mu) * rstd + bs[7];
  *(float4*)(out + (size_t)row * kD + d0) = o0;
  *(float4*)(out + (size_t)row * kD + d0 + 4) = o1;
}

extern "C" void kernel_launch(void* const* d_in, const int* in_sizes, int n_in,
                              void* d_out, int out_size, void* d_ws, size_t ws_size,
                              hipStream_t stream) {
  const float* q  = (const float*)d_in[0];
  const float* k  = (const float*)d_in[1];
  const float* v  = (const float*)d_in[2];
  const int* qmask = (const int*)d_in[3];
  const int* kmask = (const int*)d_in[4];
  const float* Wq = (const float*)d_in[5];
  const float* bq = (const float*)d_in[6];
  const float* Wk = (const float*)d_in[7];
  const float* bk = (const float*)d_in[8];
  const float* Wv = (const float*)d_in[9];
  const float* bv = (const float*)d_in[10];
  const float* gamma = (const float*)d_in[11];
  const float* beta  = (const float*)d_in[12];
  float* out = (float*)d_out;
  unsigned short* wsqkv = (unsigned short*)d_ws;        // 0..24MB: Q,K,V^T bf16
  unsigned short* ybf   = wsqkv + (size_t)3 * 4194304;  // 24..32.4MB: y bf16
  unsigned short* wbf   = wsqkv + (size_t)4 * 4194304;  // 32..33.5MB: W bf16

  wcvt_kernel<<<768, 256, 0, stream>>>(Wq, Wk, Wv, wbf);
  qkv_gemm_kernel<<<768, 256, 0, stream>>>(
      q, k, v, wbf, bq, bk, bv, wsqkv);
  attn_kernel<<<512, 256, 0, stream>>>(wsqkv, kmask, ybf);
  ln_kernel<<<2048, 256, 0, stream>>>(ybf, q, qmask, gamma, beta, out);
}

// Round 22
// 68.052 us; speedup vs baseline: 1.0530x; 1.0530x over previous
//
#include <hip/hip_runtime.h>
#include <hip/hip_bf16.h>
#include <stdint.h>

constexpr int kB = 8, kH = 8, kS = 1024, kD = 512, kDH = 64;
constexpr float kNeg = -1e9f;
constexpr float kScaleLog2e = 0.125f * 1.4426950408889634f;

typedef __attribute__((ext_vector_type(8))) short bf16x8;
typedef __attribute__((ext_vector_type(8))) unsigned short u16x8;
typedef __attribute__((ext_vector_type(4))) float f32x4;
typedef __attribute__((ext_vector_type(4))) unsigned short u16x4;

__device__ __forceinline__ unsigned short f2bf(float f) {
  union { float f; unsigned int u; } a; a.f = f;
  return (unsigned short)((a.u + 0x7FFFu + ((a.u >> 16) & 1u)) >> 16);
}
__device__ __forceinline__ float bf2f(unsigned short u) {
  union { unsigned int u; float f; } a; a.u = ((unsigned int)u) << 16;
  return a.f;
}
__device__ __forceinline__ unsigned int pk2bf(float lo, float hi) {
  union { __hip_bfloat162 h; unsigned int u; } cv;
  cv.h = __float22bfloat162_rn(make_float2(lo, hi));
  return cv.u;
}
// Pinned global loads (inline asm: cannot be sunk/CSE'd/re-materialized).
__device__ __forceinline__ uint4 gload16(const void* p) {
  uint4 r;
  asm volatile("global_load_dwordx4 %0, %1, off" : "=v"(r) : "v"(p));
  return r;
}
__device__ __forceinline__ int gload4(const void* p) {
  int r;
  asm volatile("global_load_dword %0, %1, off" : "=v"(r) : "v"(p));
  return r;
}
#define WAIT_VMCNT(N) do { \
  asm volatile("s_waitcnt vmcnt(" #N ")" ::: "memory"); \
  __builtin_amdgcn_sched_barrier(0); } while (0)

__device__ __forceinline__ uint4 cvt4(uint4 a, uint4 b) {
  uint4 r;
  r.x = pk2bf(__uint_as_float(a.x), __uint_as_float(a.y));
  r.y = pk2bf(__uint_as_float(a.z), __uint_as_float(a.w));
  r.z = pk2bf(__uint_as_float(b.x), __uint_as_float(b.y));
  r.w = pk2bf(__uint_as_float(b.z), __uint_as_float(b.w));
  return r;
}

#if __has_builtin(__builtin_amdgcn_exp2f)
#define EXP2F(x) __builtin_amdgcn_exp2f(x)
#else
#define EXP2F(x) exp2f(x)
#endif

// ---------------------------------------------------------------------------
// Kernel 1: C = relu(X @ W^T + bias). R19 verbatim (measured-best total):
// phase-split schedule (4 phases/K-step: ds_read frags; issue 4/16 next-tile
// pinned loads; setprio(1); 8 MFMA; setprio(0); barrier), W f32->bf16 fused
// into B staging, 2-deep pinned prefetch with counted vmcnt(16).
//   Q,K: [b*H+h][s][64]; V: [b*H+h][d][s] with s k-permuted per 64-block.
// ---------------------------------------------------------------------------
__global__ __launch_bounds__(256)
void qkv_gemm_kernel(const float* __restrict__ xq, const float* __restrict__ xk,
                     const float* __restrict__ xv,
                     const float* __restrict__ wq, const float* __restrict__ wk,
                     const float* __restrict__ wv,
                     const float* __restrict__ bq, const float* __restrict__ bk,
                     const float* __restrict__ bv,
                     unsigned short* __restrict__ wsout)
{
  __shared__ __align__(16) unsigned short As[2][128][72];
  __shared__ __align__(16) unsigned short Bs[2][128][72];

  const int bid = blockIdx.x;
  const int xcd = bid & 7;
  const int j = bid >> 3;
  const int x = j & 3;
  const int g = (j >> 2) * 8 + xcd;        // 0..191
  const int z = g >> 6;                    // 0..2
  const int y = g & 63;                    // 0..63

  const float* X    = (z == 0) ? xq : (z == 1) ? xk : xv;
  const float* W    = (z == 0) ? wq : (z == 1) ? wk : wv;
  const float* bias = (z == 0) ? bq : (z == 1) ? bk : bv;
  unsigned short* out = wsout + (size_t)z * (kB * kS * kD);

  const int m0 = y * 128;
  const int n0 = x * 128;
  const int t = threadIdx.x;
  const int lane = t & 63;
  const int w = t >> 6;
  const int wr = w >> 1, wc = w & 1;
  const int l16 = lane & 15, lg = lane >> 4;

  const int row = t >> 3, c8 = (t & 7) * 8;
  const float* Xr = X + (size_t)(m0 + row) * kD + c8;
  const float* Wr = W + (size_t)(n0 + row) * kD + c8;

  f32x4 acc[4][4] = {};
  uint4 pa0, pa1, pa2, pa3, pa4, pa5, pa6, pa7;
  uint4 pb0l, pb0h, pb1l, pb1h, pb2l, pb2h, pb3l, pb3h;
  uint4 qa0, qa1, qa2, qa3, qa4, qa5, qa6, qa7;
  uint4 qb0l, qb0h, qb1l, qb1h, qb2l, qb2h, qb3l, qb3h;

  auto issueP = [&](int kt) {
    pa0 = gload16(Xr + kt);            pa1 = gload16(Xr + kt + 4);
    pa2 = gload16(Xr + 32 * kD + kt);  pa3 = gload16(Xr + 32 * kD + kt + 4);
    pa4 = gload16(Xr + 64 * kD + kt);  pa5 = gload16(Xr + 64 * kD + kt + 4);
    pa6 = gload16(Xr + 96 * kD + kt);  pa7 = gload16(Xr + 96 * kD + kt + 4);
    pb0l = gload16(Wr + kt);            pb0h = gload16(Wr + kt + 4);
    pb1l = gload16(Wr + 32 * kD + kt);  pb1h = gload16(Wr + 32 * kD + kt + 4);
    pb2l = gload16(Wr + 64 * kD + kt);  pb2h = gload16(Wr + 64 * kD + kt + 4);
    pb3l = gload16(Wr + 96 * kD + kt);  pb3h = gload16(Wr + 96 * kD + kt + 4);
  };
  auto issueQ = [&](int kt) {
    qa0 = gload16(Xr + kt);            qa1 = gload16(Xr + kt + 4);
    qa2 = gload16(Xr + 32 * kD + kt);  qa3 = gload16(Xr + 32 * kD + kt + 4);
    qa4 = gload16(Xr + 64 * kD + kt);  qa5 = gload16(Xr + 64 * kD + kt + 4);
    qa6 = gload16(Xr + 96 * kD + kt);  qa7 = gload16(Xr + 96 * kD + kt + 4);
    qb0l = gload16(Wr + kt);            qb0h = gload16(Wr + kt + 4);
    qb1l = gload16(Wr + 32 * kD + kt);  qb1h = gload16(Wr + 32 * kD + kt + 4);
    qb2l = gload16(Wr + 64 * kD + kt);  qb2h = gload16(Wr + 64 * kD + kt + 4);
    qb3l = gload16(Wr + 96 * kD + kt);  qb3h = gload16(Wr + 96 * kD + kt + 4);
  };
  auto issueP1 = [&](int kt) {
    pa0 = gload16(Xr + kt);            pa1 = gload16(Xr + kt + 4);
    pa2 = gload16(Xr + 32 * kD + kt);  pa3 = gload16(Xr + 32 * kD + kt + 4);
  };
  auto issueP2 = [&](int kt) {
    pa4 = gload16(Xr + 64 * kD + kt);  pa5 = gload16(Xr + 64 * kD + kt + 4);
    pa6 = gload16(Xr + 96 * kD + kt);  pa7 = gload16(Xr + 96 * kD + kt + 4);
  };
  auto issueP3 = [&](int kt) {
    pb0l = gload16(Wr + kt);            pb0h = gload16(Wr + kt + 4);
    pb1l = gload16(Wr + 32 * kD + kt);  pb1h = gload16(Wr + 32 * kD + kt + 4);
  };
  auto issueP4 = [&](int kt) {
    pb2l = gload16(Wr + 64 * kD + kt);  pb2h = gload16(Wr + 64 * kD + kt + 4);
    pb3l = gload16(Wr + 96 * kD + kt);  pb3h = gload16(Wr + 96 * kD + kt + 4);
  };
  auto issueQ1 = [&](int kt) {
    qa0 = gload16(Xr + kt);            qa1 = gload16(Xr + kt + 4);
    qa2 = gload16(Xr + 32 * kD + kt);  qa3 = gload16(Xr + 32 * kD + kt + 4);
  };
  auto issueQ2 = [&](int kt) {
    qa4 = gload16(Xr + 64 * kD + kt);  qa5 = gload16(Xr + 64 * kD + kt + 4);
    qa6 = gload16(Xr + 96 * kD + kt);  qa7 = gload16(Xr + 96 * kD + kt + 4);
  };
  auto issueQ3 = [&](int kt) {
    qb0l = gload16(Wr + kt);            qb0h = gload16(Wr + kt + 4);
    qb1l = gload16(Wr + 32 * kD + kt);  qb1h = gload16(Wr + 32 * kD + kt + 4);
  };
  auto issueQ4 = [&](int kt) {
    qb2l = gload16(Wr + 64 * kD + kt);  qb2h = gload16(Wr + 64 * kD + kt + 4);
    qb3l = gload16(Wr + 96 * kD + kt);  qb3h = gload16(Wr + 96 * kD + kt + 4);
  };
  auto writeP = [&]() {
    *(uint4*)&As[0][row][c8]      = cvt4(pa0, pa1);
    *(uint4*)&As[0][row + 32][c8] = cvt4(pa2, pa3);
    *(uint4*)&As[0][row + 64][c8] = cvt4(pa4, pa5);
    *(uint4*)&As[0][row + 96][c8] = cvt4(pa6, pa7);
    *(uint4*)&Bs[0][row][c8]      = cvt4(pb0l, pb0h);
    *(uint4*)&Bs[0][row + 32][c8] = cvt4(pb1l, pb1h);
    *(uint4*)&Bs[0][row + 64][c8] = cvt4(pb2l, pb2h);
    *(uint4*)&Bs[0][row + 96][c8] = cvt4(pb3l, pb3h);
  };
  auto writeQ = [&]() {
    *(uint4*)&As[1][row][c8]      = cvt4(qa0, qa1);
    *(uint4*)&As[1][row + 32][c8] = cvt4(qa2, qa3);
    *(uint4*)&As[1][row + 64][c8] = cvt4(qa4, qa5);
    *(uint4*)&As[1][row + 96][c8] = cvt4(qa6, qa7);
    *(uint4*)&Bs[1][row][c8]      = cvt4(qb0l, qb0h);
    *(uint4*)&Bs[1][row + 32][c8] = cvt4(qb1l, qb1h);
    *(uint4*)&Bs[1][row + 64][c8] = cvt4(qb2l, qb2h);
    *(uint4*)&Bs[1][row + 96][c8] = cvt4(qb3l, qb3h);
  };

#define COMPUTE_PHASED(BUF, KT, I1, I2, I3, I4)                               \
  do {                                                                        \
    bf16x8 av0, av1, av2, av3, bv0, bv1;                                      \
    av0 = *(const bf16x8*)&As[BUF][wr * 64 +  0 + l16][lg * 8];               \
    av1 = *(const bf16x8*)&As[BUF][wr * 64 + 16 + l16][lg * 8];               \
    av2 = *(const bf16x8*)&As[BUF][wr * 64 + 32 + l16][lg * 8];               \
    av3 = *(const bf16x8*)&As[BUF][wr * 64 + 48 + l16][lg * 8];               \
    bv0 = *(const bf16x8*)&Bs[BUF][wc * 64 +  0 + l16][lg * 8];               \
    bv1 = *(const bf16x8*)&Bs[BUF][wc * 64 + 16 + l16][lg * 8];               \
    if (KT >= 0) I1(KT);                                                      \
    __builtin_amdgcn_s_setprio(1);                                            \
    acc[0][0] = __builtin_amdgcn_mfma_f32_16x16x32_bf16(bv0, av0, acc[0][0], 0, 0, 0); \
    acc[1][0] = __builtin_amdgcn_mfma_f32_16x16x32_bf16(bv0, av1, acc[1][0], 0, 0, 0); \
    acc[2][0] = __builtin_amdgcn_mfma_f32_16x16x32_bf16(bv0, av2, acc[2][0], 0, 0, 0); \
    acc[3][0] = __builtin_amdgcn_mfma_f32_16x16x32_bf16(bv0, av3, acc[3][0], 0, 0, 0); \
    acc[0][1] = __builtin_amdgcn_mfma_f32_16x16x32_bf16(bv1, av0, acc[0][1], 0, 0, 0); \
    acc[1][1] = __builtin_amdgcn_mfma_f32_16x16x32_bf16(bv1, av1, acc[1][1], 0, 0, 0); \
    acc[2][1] = __builtin_amdgcn_mfma_f32_16x16x32_bf16(bv1, av2, acc[2][1], 0, 0, 0); \
    acc[3][1] = __builtin_amdgcn_mfma_f32_16x16x32_bf16(bv1, av3, acc[3][1], 0, 0, 0); \
    __builtin_amdgcn_s_setprio(0);                                            \
    __syncthreads();                                                          \
    bv0 = *(const bf16x8*)&Bs[BUF][wc * 64 + 32 + l16][lg * 8];               \
    bv1 = *(const bf16x8*)&Bs[BUF][wc * 64 + 48 + l16][lg * 8];               \
    if (KT >= 0) I2(KT);                                                      \
    __builtin_amdgcn_s_setprio(1);                                            \
    acc[0][2] = __builtin_amdgcn_mfma_f32_16x16x32_bf16(bv0, av0, acc[0][2], 0, 0, 0); \
    acc[1][2] = __builtin_amdgcn_mfma_f32_16x16x32_bf16(bv0, av1, acc[1][2], 0, 0, 0); \
    acc[2][2] = __builtin_amdgcn_mfma_f32_16x16x32_bf16(bv0, av2, acc[2][2], 0, 0, 0); \
    acc[3][2] = __builtin_amdgcn_mfma_f32_16x16x32_bf16(bv0, av3, acc[3][2], 0, 0, 0); \
    acc[0][3] = __builtin_amdgcn_mfma_f32_16x16x32_bf16(bv1, av0, acc[0][3], 0, 0, 0); \
    acc[1][3] = __builtin_amdgcn_mfma_f32_16x16x32_bf16(bv1, av1, acc[1][3], 0, 0, 0); \
    acc[2][3] = __builtin_amdgcn_mfma_f32_16x16x32_bf16(bv1, av2, acc[2][3], 0, 0, 0); \
    acc[3][3] = __builtin_amdgcn_mfma_f32_16x16x32_bf16(bv1, av3, acc[3][3], 0, 0, 0); \
    __builtin_amdgcn_s_setprio(0);                                            \
    __syncthreads();                                                          \
    av0 = *(const bf16x8*)&As[BUF][wr * 64 +  0 + l16][32 + lg * 8];          \
    av1 = *(const bf16x8*)&As[BUF][wr * 64 + 16 + l16][32 + lg * 8];          \
    av2 = *(const bf16x8*)&As[BUF][wr * 64 + 32 + l16][32 + lg * 8];          \
    av3 = *(const bf16x8*)&As[BUF][wr * 64 + 48 + l16][32 + lg * 8];          \
    bv0 = *(const bf16x8*)&Bs[BUF][wc * 64 +  0 + l16][32 + lg * 8];          \
    bv1 = *(const bf16x8*)&Bs[BUF][wc * 64 + 16 + l16][32 + lg * 8];          \
    if (KT >= 0) I3(KT);                                                      \
    __builtin_amdgcn_s_setprio(1);                                            \
    acc[0][0] = __builtin_amdgcn_mfma_f32_16x16x32_bf16(bv0, av0, acc[0][0], 0, 0, 0); \
    acc[1][0] = __builtin_amdgcn_mfma_f32_16x16x32_bf16(bv0, av1, acc[1][0], 0, 0, 0); \
    acc[2][0] = __builtin_amdgcn_mfma_f32_16x16x32_bf16(bv0, av2, acc[2][0], 0, 0, 0); \
    acc[3][0] = __builtin_amdgcn_mfma_f32_16x16x32_bf16(bv0, av3, acc[3][0], 0, 0, 0); \
    acc[0][1] = __builtin_amdgcn_mfma_f32_16x16x32_bf16(bv1, av0, acc[0][1], 0, 0, 0); \
    acc[1][1] = __builtin_amdgcn_mfma_f32_16x16x32_bf16(bv1, av1, acc[1][1], 0, 0, 0); \
    acc[2][1] = __builtin_amdgcn_mfma_f32_16x16x32_bf16(bv1, av2, acc[2][1], 0, 0, 0); \
    acc[3][1] = __builtin_amdgcn_mfma_f32_16x16x32_bf16(bv1, av3, acc[3][1], 0, 0, 0); \
    __builtin_amdgcn_s_setprio(0);                                            \
    __syncthreads();                                                          \
    bv0 = *(const bf16x8*)&Bs[BUF][wc * 64 + 32 + l16][32 + lg * 8];          \
    bv1 = *(const bf16x8*)&Bs[BUF][wc * 64 + 48 + l16][32 + lg * 8];          \
    if (KT >= 0) I4(KT);                                                      \
    __builtin_amdgcn_s_setprio(1);                                            \
    acc[0][2] = __builtin_amdgcn_mfma_f32_16x16x32_bf16(bv0, av0, acc[0][2], 0, 0, 0); \
    acc[1][2] = __builtin_amdgcn_mfma_f32_16x16x32_bf16(bv0, av1, acc[1][2], 0, 0, 0); \
    acc[2][2] = __builtin_amdgcn_mfma_f32_16x16x32_bf16(bv0, av2, acc[2][2], 0, 0, 0); \
    acc[3][2] = __builtin_amdgcn_mfma_f32_16x16x32_bf16(bv0, av3, acc[3][2], 0, 0, 0); \
    acc[0][3] = __builtin_amdgcn_mfma_f32_16x16x32_bf16(bv1, av0, acc[0][3], 0, 0, 0); \
    acc[1][3] = __builtin_amdgcn_mfma_f32_16x16x32_bf16(bv1, av1, acc[1][3], 0, 0, 0); \
    acc[2][3] = __builtin_amdgcn_mfma_f32_16x16x32_bf16(bv1, av2, acc[2][3], 0, 0, 0); \
    acc[3][3] = __builtin_amdgcn_mfma_f32_16x16x32_bf16(bv1, av3, acc[3][3], 0, 0, 0); \
    __builtin_amdgcn_s_setprio(0);                                            \
  } while (0)

  issueP(0);
  issueQ(64);
#pragma unroll
  for (int i = 0; i < 6; i += 2) {
    WAIT_VMCNT(16);
    writeP();
    __syncthreads();
    COMPUTE_PHASED(0, (i + 2) * 64, issueP1, issueP2, issueP3, issueP4);
    WAIT_VMCNT(16);
    writeQ();
    __syncthreads();
    COMPUTE_PHASED(1, (i + 3) * 64, issueQ1, issueQ2, issueQ3, issueQ4);
  }
  WAIT_VMCNT(16);
  writeP();
  __syncthreads();
  COMPUTE_PHASED(0, -1, issueP1, issueP2, issueP3, issueP4);
  WAIT_VMCNT(0);
  writeQ();
  __syncthreads();
  COMPUTE_PHASED(1, -1, issueQ1, issueQ2, issueQ3, issueQ4);
#undef COMPUTE_PHASED

  if (z == 2) {
    const int mmbase = m0 + wr * 64;
    const int b_ = mmbase >> 10, sbase = mmbase & 1023;
#pragma unroll
    for (int nf = 0; nf < 4; ++nf) {
#pragma unroll
      for (int r = 0; r < 4; ++r) {
        const int n = n0 + wc * 64 + nf * 16 + lg * 4 + r;
        const float bval = bias[n];
        const int h = n >> 6, dd = n & 63;
        u16x4 pk;
#pragma unroll
        for (int mf = 0; mf < 4; ++mf) {
          float vv = acc[mf][nf][r] + bval;
          vv = vv > 0.f ? vv : 0.f;
          pk[mf] = f2bf(vv);
        }
        *(u16x4*)&out[((size_t)((b_ * kH + h) * kDH + dd)) * kS + sbase + l16 * 4] = pk;
      }
    }
  } else {
#pragma unroll
    for (int mf = 0; mf < 4; ++mf) {
      const int mm = m0 + wr * 64 + mf * 16 + l16;
      const int b_ = mm >> 10, s = mm & 1023;
#pragma unroll
      for (int nf = 0; nf < 4; ++nf) {
        const int nbase = n0 + wc * 64 + nf * 16 + lg * 4;
        const int h = nbase >> 6, dd = nbase & 63;
        u16x4 pk;
#pragma unroll
        for (int r = 0; r < 4; ++r) {
          float vv = acc[mf][nf][r] + bias[nbase + r];
          vv = vv > 0.f ? vv : 0.f;
          pk[r] = f2bf(vv);
        }
        *(u16x4*)&out[((size_t)(b_ * kH + h) * kS + s) * kDH + dd] = pk;
      }
    }
  }
}

// ---------------------------------------------------------------------------
// Kernel 2: flash attention (R19 verbatim: pad-68 LDS = 51.5KB = 3 blk/CU,
// T5 setprio, bf16 y). 512 blocks (bh x 8 q-tiles of 128 rows), 4 waves x
// 32 q-rows; 2-deep pinned prefetch, counted vmcnt(5); LDS dbuf.
// ---------------------------------------------------------------------------
__global__ __launch_bounds__(256)
void attn_kernel(const unsigned short* __restrict__ ws,
                 const int* __restrict__ key_mask,
                 unsigned short* __restrict__ ybf)
{
  __shared__ __align__(16) unsigned short Ks[2][64][68];
  __shared__ __align__(16) unsigned short Vts[2][64][68];
  __shared__ __align__(16) unsigned short Ps[4][32][68];
  __shared__ float kmadd[2][64];

  const unsigned short* Qw = ws;
  const unsigned short* Kw = ws + (size_t)1 * kB * kS * kD;
  const unsigned short* Vw = ws + (size_t)2 * kB * kS * kD;

  const int bid = blockIdx.x;
  const int xcd = bid & 7;
  const int j = bid >> 3;
  const int qx = j & 7;
  const int bh = (j >> 3) * 8 + xcd;

  const int q0 = qx * 128;
  const int t = threadIdx.x;
  const int w = t >> 6, lane = t & 63;
  const int l16 = lane & 15, lg = lane >> 4;
  const int b_ = bh / kH, h = bh % kH;

  const unsigned short* Qb = Qw + ((size_t)bh * kS + q0) * kDH;
  const unsigned short* Kb = Kw + (size_t)bh * kS * kDH;
  const unsigned short* Vb = Vw + (size_t)bh * kDH * kS;
  const int* km = key_mask + (bh % kB) * kS;

  const int srow = t >> 3, sc8 = (t & 7) * 8;
  const unsigned short* KbR0 = Kb + (size_t)srow * kDH + sc8;
  const unsigned short* KbR1 = Kb + (size_t)(srow + 32) * kDH + sc8;
  const unsigned short* VbR0 = Vb + (size_t)srow * kS + sc8;
  const unsigned short* VbR1 = Vb + (size_t)(srow + 32) * kS + sc8;

  bf16x8 aq[2][2];
#pragma unroll
  for (int u = 0; u < 2; ++u)
#pragma unroll
    for (int kk = 0; kk < 2; ++kk)
      aq[u][kk] = *(const bf16x8*)(Qb + (size_t)(w * 32 + u * 16 + l16) * kDH + kk * 32 + lg * 8);

  bf16x8 vone;
#pragma unroll
  for (int jj = 0; jj < 8; ++jj) vone[jj] = (short)0x3F80;

  f32x4 o[2][4] = {};
  f32x4 lacc[2] = {};

  uint4 ka0, ka1, va0, va1; int kma;
  uint4 kb0, kb1, vb0, vb1; int kmb;

  auto issueA = [&](int kv0) {
    ka0 = gload16(KbR0 + (size_t)kv0 * kDH);
    ka1 = gload16(KbR1 + (size_t)kv0 * kDH);
    va0 = gload16(VbR0 + kv0);
    va1 = gload16(VbR1 + kv0);
    kma = gload4(km + kv0 + (t & 63));
  };
  auto issueB = [&](int kv0) {
    kb0 = gload16(KbR0 + (size_t)kv0 * kDH);
    kb1 = gload16(KbR1 + (size_t)kv0 * kDH);
    vb0 = gload16(VbR0 + kv0);
    vb1 = gload16(VbR1 + kv0);
    kmb = gload4(km + kv0 + (t & 63));
  };
  auto writeA = [&]() {
    *(uint4*)&Ks[0][srow][sc8]       = ka0;
    *(uint4*)&Ks[0][srow + 32][sc8]  = ka1;
    *(uint4*)&Vts[0][srow][sc8]      = va0;
    *(uint4*)&Vts[0][srow + 32][sc8] = va1;
    if (t < 64) kmadd[0][t] = kma ? 0.f : kNeg;
  };
  auto writeB = [&]() {
    *(uint4*)&Ks[1][srow][sc8]       = kb0;
    *(uint4*)&Ks[1][srow + 32][sc8]  = kb1;
    *(uint4*)&Vts[1][srow][sc8]      = vb0;
    *(uint4*)&Vts[1][srow + 32][sc8] = vb1;
    if (t < 64) kmadd[1][t] = kmb ? 0.f : kNeg;
  };
  auto compute = [&](int buf) {
    f32x4 sc[2][4] = {};
    __builtin_amdgcn_s_setprio(1);
#pragma unroll
    for (int kk = 0; kk < 2; ++kk) {
#pragma unroll
      for (int nf = 0; nf < 4; ++nf) {
        bf16x8 bfr = *(const bf16x8*)&Ks[buf][nf * 16 + l16][kk * 32 + lg * 8];
#pragma unroll
        for (int u = 0; u < 2; ++u)
          sc[u][nf] = __builtin_amdgcn_mfma_f32_16x16x32_bf16(aq[u][kk], bfr, sc[u][nf], 0, 0, 0);
      }
    }
    __builtin_amdgcn_s_setprio(0);
    float madd[4];
#pragma unroll
    for (int nf = 0; nf < 4; ++nf) madd[nf] = kmadd[buf][nf * 16 + l16];
#pragma unroll
    for (int u = 0; u < 2; ++u) {
#pragma unroll
      for (int r = 0; r < 4; ++r) {
        const float p0 = EXP2F(fmaf(sc[u][0][r], kScaleLog2e, madd[0]));
        const float p1 = EXP2F(fmaf(sc[u][1][r], kScaleLog2e, madd[1]));
        const float p2 = EXP2F(fmaf(sc[u][2][r], kScaleLog2e, madd[2]));
        const float p3 = EXP2F(fmaf(sc[u][3][r], kScaleLog2e, madd[3]));
        const int prow = u * 16 + lg * 4 + r;
        uint2 pw;
        pw.x = __builtin_amdgcn_perm(__float_as_uint(p1), __float_as_uint(p0), 0x07060302u);
        pw.y = __builtin_amdgcn_perm(__float_as_uint(p3), __float_as_uint(p2), 0x07060302u);
        *(uint2*)&Ps[w][prow][l16 * 4] = pw;
      }
    }
    __builtin_amdgcn_s_setprio(1);
#pragma unroll
    for (int kk = 0; kk < 2; ++kk) {
      bf16x8 a0 = *(const bf16x8*)&Ps[w][l16][kk * 32 + lg * 8];
      bf16x8 a1 = *(const bf16x8*)&Ps[w][16 + l16][kk * 32 + lg * 8];
#pragma unroll
      for (int nd = 0; nd < 4; ++nd) {
        bf16x8 bfr = *(const bf16x8*)&Vts[buf][nd * 16 + l16][kk * 32 + lg * 8];
        o[0][nd] = __builtin_amdgcn_mfma_f32_16x16x32_bf16(a0, bfr, o[0][nd], 0, 0, 0);
        o[1][nd] = __builtin_amdgcn_mfma_f32_16x16x32_bf16(a1, bfr, o[1][nd], 0, 0, 0);
      }
      lacc[0] = __builtin_amdgcn_mfma_f32_16x16x32_bf16(a0, vone, lacc[0], 0, 0, 0);
      lacc[1] = __builtin_amdgcn_mfma_f32_16x16x32_bf16(a1, vone, lacc[1], 0, 0, 0);
    }
    __builtin_amdgcn_s_setprio(0);
  };

  issueA(0);
  issueB(64);
  for (int i = 0; i < 14; i += 2) {
    WAIT_VMCNT(5);
    writeA();
    issueA((i + 2) * 64);
    __syncthreads();
    compute(0);
    WAIT_VMCNT(5);
    writeB();
    issueB((i + 3) * 64);
    __syncthreads();
    compute(1);
  }
  WAIT_VMCNT(5);
  writeA();
  __syncthreads();
  compute(0);
  WAIT_VMCNT(0);
  writeB();
  __syncthreads();
  compute(1);

#pragma unroll
  for (int u = 0; u < 2; ++u) {
    float rinv[4];
#pragma unroll
    for (int r = 0; r < 4; ++r) rinv[r] = 1.f / lacc[u][r];
#pragma unroll
    for (int nd = 0; nd < 4; ++nd) {
#pragma unroll
      for (int r = 0; r < 4; ++r) {
        const int srowq = q0 + w * 32 + u * 16 + lg * 4 + r;
        ybf[((size_t)b_ * kS + srowq) * kD + h * kDH + nd * 16 + l16] =
            f2bf(o[u][nd][r] * rinv[r]);
      }
    }
  }
}

// ---------------------------------------------------------------------------
// Kernel 3: out = LN(qmask*y + q) * gamma + beta. y read as bf16 from ws.
// ---------------------------------------------------------------------------
__global__ __launch_bounds__(256)
void ln_kernel(const unsigned short* __restrict__ ybf, const float* __restrict__ q,
               const int* __restrict__ qmask,
               const float* __restrict__ gamma, const float* __restrict__ beta,
               float* __restrict__ out)
{
  const int w = threadIdx.x >> 6, lane = threadIdx.x & 63;
  const int row = blockIdx.x * 4 + w;            // 0..8191
  const int b_ = row >> 10, s = row & 1023;
  const int d0 = lane * 8;
  const int h = d0 >> 6;

  const unsigned short* yp = ybf + (size_t)row * kD + d0;
  const float* qp = q + (size_t)row * kD + d0;
  const int qm = qmask[((b_ * kH + h) % kB) * kS + s];

  u16x8 yv = *(const u16x8*)yp;
  float4 q0 = *(const float4*)qp, q1 = *(const float4*)(qp + 4);
  float vals[8];
#pragma unroll
  for (int jj = 0; jj < 8; ++jj) vals[jj] = bf2f(yv[jj]);
  float qs[8]   = { q0.x, q0.y, q0.z, q0.w, q1.x, q1.y, q1.z, q1.w };

  float sum = 0.f, ss = 0.f;
#pragma unroll
  for (int jj = 0; jj < 8; ++jj) {
    const float val = (qm ? vals[jj] : 0.f) + qs[jj];
    vals[jj] = val; sum += val; ss += val * val;
  }
#pragma unroll
  for (int off = 1; off < 64; off <<= 1) {
    sum += __shfl_xor(sum, off);
    ss  += __shfl_xor(ss, off);
  }
  const float mu = sum * (1.f / kD);
  const float var = ss * (1.f / kD) - mu * mu;
  const float rstd = rsqrtf(var + 1e-6f);

  float4 g0 = *(const float4*)(gamma + d0), g1 = *(const float4*)(gamma + d0 + 4);
  float4 be0 = *(const float4*)(beta + d0), be1 = *(const float4*)(beta + d0 + 4);
  float gs[8] = { g0.x, g0.y, g0.z, g0.w, g1.x, g1.y, g1.z, g1.w };
  float bs[8] = { be0.x, be0.y, be0.z, be0.w, be1.x, be1.y, be1.z, be1.w };

  float4 o0, o1;
  o0.x = gs[0] * (vals[0] - mu) * rstd + bs[0];
  o0.y = gs[1] * (vals[1] - mu) * rstd + bs[1];
  o0.z = gs[2] * (vals[2] - mu) * rstd + bs[2];
  o0.w = gs[3] * (vals[3] - mu) * rstd + bs[3];
  o1.x = gs[4] * (vals[4] - mu) * rstd + bs[4];
  o1.y = gs[5] * (vals[5] - mu) * rstd + bs[5];
  o1.z = gs[6] * (vals[6] - mu) * rstd + bs[6];
  o1.w = gs[7] * (vals[7] - mu) * rstd + bs[7];
  *(float4*)(out + (size_t)row * kD + d0) = o0;
  *(float4*)(out + (size_t)row * kD + d0 + 4) = o1;
}

extern "C" void kernel_launch(void* const* d_in, const int* in_sizes, int n_in,
                              void* d_out, int out_size, void* d_ws, size_t ws_size,
                              hipStream_t stream) {
  const float* q  = (const float*)d_in[0];
  const float* k  = (const float*)d_in[1];
  const float* v  = (const float*)d_in[2];
  const int* qmask = (const int*)d_in[3];
  const int* kmask = (const int*)d_in[4];
  const float* Wq = (const float*)d_in[5];
  const float* bq = (const float*)d_in[6];
  const float* Wk = (const float*)d_in[7];
  const float* bk = (const float*)d_in[8];
  const float* Wv = (const float*)d_in[9];
  const float* bv = (const float*)d_in[10];
  const float* gamma = (const float*)d_in[11];
  const float* beta  = (const float*)d_in[12];
  float* out = (float*)d_out;
  unsigned short* wsqkv = (unsigned short*)d_ws;        // 0..24MB: Q,K,V^T bf16
  unsigned short* ybf   = wsqkv + (size_t)3 * 4194304;  // 24..32.4MB: y bf16

  qkv_gemm_kernel<<<768, 256, 0, stream>>>(
      q, k, v, Wq, Wk, Wv, bq, bk, bv, wsqkv);
  attn_kernel<<<512, 256, 0, stream>>>(wsqkv, kmask, ybf);
  ln_kernel<<<2048, 256, 0, stream>>>(ybf, q, qmask, gamma, beta, out);
}